// Round 12
// baseline (216.583 us; speedup 1.0000x reference)
//
#include <hip/hip_runtime.h>
#include <hip/hip_bf16.h>

#define N 2048

using f32x2  = __attribute__((ext_vector_type(2))) float;
using f32x4  = __attribute__((ext_vector_type(4))) float;
using short8 = __attribute__((ext_vector_type(8))) short;

// async global->LDS, 16B per lane; LDS dest = wave-uniform base + lane*16
#define GLOAD_LDS16(dst, src)                                                        \
  __builtin_amdgcn_global_load_lds((const __attribute__((address_space(1))) void*)(src), \
                                   (__attribute__((address_space(3))) void*)(dst), 16, 0, 0)

// ---------------------------------------------------------------------------
// Kernel 0: weights-only prep (1 block).  W2 -> bf16 [32][128]; W1,b1 pre-
// scaled by -log2(e) so the MLP inner loop feeds v_exp_f32 (2^t' = e^-t).
// ---------------------------------------------------------------------------
__global__ void prep_w(const float* __restrict__ W2, const float* __restrict__ W1,
                       const float* __restrict__ b1,
                       __hip_bfloat16* __restrict__ W2b,
                       float* __restrict__ W1n, float* __restrict__ b1n) {
  const int tid = threadIdx.x;   // 256 threads
  const float c = -1.4426950408889634f;  // -log2(e)
#pragma unroll
  for (int q = 0; q < 16; ++q)
    W2b[q * 256 + tid] = __float2bfloat16(W2[q * 256 + tid]);
  W1n[tid] = W1[tid] * c;
  if (tid < 128) b1n[tid] = b1[tid] * c;
}

// ---------------------------------------------------------------------------
// Kernel 1: build A = K^T (bf16) with MFMA layer-2.  BYTE-IDENTICAL to
// round-9 (passed, 90.4 us).  Grid 8704: t < 8256 upper-tri MLP blocks;
// t >= 8256 band-zero blocks covering every lower-triangle element the
// gemm's k-clip can read.
// ---------------------------------------------------------------------------
__global__ __launch_bounds__(256) void build_A_mfma(
    const float* __restrict__ x,
    const float* __restrict__ W1n,             // [128][2], pre-scaled -log2e
    const float* __restrict__ b1n,             // [128],    pre-scaled -log2e
    const __hip_bfloat16* __restrict__ W2b,    // [32][128] bf16
    const float* __restrict__ b2,              // [32]
    const float* __restrict__ W3,              // [32]
    const float* __restrict__ b3,              // [1]
    __hip_bfloat16* __restrict__ A)            // [N][N], A[j][i]
{
  const int t = blockIdx.x;
  const int tid = threadIdx.x;

  if (t >= 8256) {               // band-zero block
    const int z = t - 8256;      // 0..447
    const int p = z / 28, q = z % 28;
    int r = 1;                    // decode strict lower-tri pair (r > c) from q
    while ((r * (r + 1)) / 2 <= q) ++r;       // r in 1..7
    const int c2 = q - (r * (r - 1)) / 2;     // c in 0..r-1
    const int jj = (p * 8 + c2) * 16 + (tid >> 4);   // row j (block bj = c2 < r)
    const int ii = (p * 8 + r) * 16 + (tid & 15);    // col i (block bi = r)
    A[(size_t)jj * N + ii] = __float2bfloat16(0.0f); // i > j here always
    return;
  }

  // decode linear upper-tri block id: t = bj*(bj+1)/2 + bi, bi <= bj
  int bj = (int)((sqrtf(8.0f * (float)t + 1.0f) - 1.0f) * 0.5f);
  while ((bj + 1) * (bj + 2) / 2 <= t) ++bj;
  while (bj * (bj + 1) / 2 > t) --bj;
  const int bi = t - bj * (bj + 1) / 2;

  const int i0 = bi * 16, j0 = bj * 16;

  __shared__ float w1s[256];   // [k][2] pre-scaled
  __shared__ float b1s[128];
  w1s[tid] = W1n[tid & 255];
  if (tid < 128) b1s[tid] = b1n[tid];
  __syncthreads();

  const int w  = tid >> 6;
  const int l  = tid & 63;
  const int lm = l & 15;       // A-frag row (i-slot) / C col (o)
  const int lk = l >> 4;       // k-block-of-8 / C row-group

  const float xi = x[i0 + lm];
  float xj[4];
#pragma unroll
  for (int m = 0; m < 4; ++m) xj[m] = x[j0 + w * 4 + m];

  // W2 fragments (B^T row-major): lane holds W2[o=g*16+lm][kb*32+lk*8 .. +7]
  short8 wf[2][4];
#pragma unroll
  for (int g = 0; g < 2; ++g)
#pragma unroll
    for (int kb = 0; kb < 4; ++kb)
      wf[g][kb] = *(const short8*)(W2b + (g * 16 + lm) * 128 + kb * 32 + lk * 8);

  const float b2v[2] = {b2[lm], b2[16 + lm]};
  f32x4 acc[4][2];
#pragma unroll
  for (int m = 0; m < 4; ++m)
#pragma unroll
    for (int g = 0; g < 2; ++g)
      acc[m][g] = (f32x4){b2v[g], b2v[g], b2v[g], b2v[g]};

#pragma unroll
  for (int kb = 0; kb < 4; ++kb) {
    // xi-dependent half of layer 1, shared across the 4 j's of this wave-slot
    f32x2 basep[4], w1bp[4];
#pragma unroll
    for (int e2 = 0; e2 < 4; ++e2) {
      const int k = kb * 32 + lk * 8 + e2 * 2;
      basep[e2] = (f32x2){fmaf(w1s[2 * k],     xi, b1s[k]),
                          fmaf(w1s[2 * k + 2], xi, b1s[k + 1])};
      w1bp[e2]  = (f32x2){w1s[2 * k + 1], w1s[2 * k + 3]};
    }
#pragma unroll
    for (int m = 0; m < 4; ++m) {
      const f32x2 xj2 = (f32x2){xj[m], xj[m]};
      __attribute__((ext_vector_type(4))) unsigned pk;
#pragma unroll
      for (int e2 = 0; e2 < 4; ++e2) {
        // h = sigmoid(t_orig) = 1/(1 + 2^t'),  t' = -log2e * t_orig
        const f32x2 t01 = __builtin_elementwise_fma(w1bp[e2], xj2, basep[e2]); // v_pk_fma_f32
        f32x2 e01;
        e01[0] = __builtin_amdgcn_exp2f(t01[0]);
        e01[1] = __builtin_amdgcn_exp2f(t01[1]);
        const f32x2 d01 = e01 + (f32x2){1.0f, 1.0f};                           // v_pk_add_f32
        const float h0 = __builtin_amdgcn_rcpf(d01[0]);   // t'->+inf: rcp(inf)=0 OK
        const float h1 = __builtin_amdgcn_rcpf(d01[1]);
        // round-half-up + perm -> [hi16(u1)|hi16(u0)]  (round-4-verified pack)
        const unsigned u0 = __builtin_bit_cast(unsigned, h0) + 0x8000u;
        const unsigned u1 = __builtin_bit_cast(unsigned, h1) + 0x8000u;
        pk[e2] = __builtin_amdgcn_perm(u1, u0, 0x07060302u);
      }
      const short8 af = __builtin_bit_cast(short8, pk);
      acc[m][0] = __builtin_amdgcn_mfma_f32_16x16x32_bf16(af, wf[0][kb], acc[m][0], 0, 0, 0);
      acc[m][1] = __builtin_amdgcn_mfma_f32_16x16x32_bf16(af, wf[1][kb], acc[m][1], 0, 0, 0);
    }
  }

  // Epilogue: v = b3 + sum_o relu(layer2[pair][o]) * W3[o]
  // C/D: row(pair) = lk*4 + r, col(o) = lm (+16 for g=1)
  const float w3a = W3[lm], w3b = W3[16 + lm];
  const float b3v = b3[0];
  const int   rsel = l & 3;

#pragma unroll
  for (int m = 0; m < 4; ++m) {
    const int j = j0 + w * 4 + m;
    float v[4];
#pragma unroll
    for (int r = 0; r < 4; ++r) {
      float s = fmaf(fmaxf(acc[m][0][r], 0.0f), w3a,
                     fmaxf(acc[m][1][r], 0.0f) * w3b);
      s += __shfl_xor(s, 1);
      s += __shfl_xor(s, 2);
      s += __shfl_xor(s, 4);
      s += __shfl_xor(s, 8);
      v[r] = s + b3v;
    }
    const float sv = rsel == 0 ? v[0] : rsel == 1 ? v[1] : rsel == 2 ? v[2] : v[3];
    const int i = i0 + lk * 4 + rsel;
    if (lm < 4)
      A[(size_t)j * N + i] = __float2bfloat16(i <= j ? sv : 0.0f);
  }
}

// ---------------------------------------------------------------------------
// Kernel 2: C = A * A^T.  BYTE-IDENTICAL to round-9 (passed).
// Launched TWICE this round (idempotent) purely for timing attribution:
// dur_us delta vs round 9 == one gemm_ata duration.
// ---------------------------------------------------------------------------
__global__ __launch_bounds__(256) void gemm_ata(
    const __hip_bfloat16* __restrict__ A, float* __restrict__ C)
{
  __shared__ __align__(16) __hip_bfloat16 As[2][128 * 32];  // 2 x 8 KB
  __shared__ __align__(16) __hip_bfloat16 Bs[2][128 * 32];  // 2 x 8 KB

  const int m0 = blockIdx.y * 128;
  const int n0 = blockIdx.x * 128;
  const int tid = threadIdx.x;
  const int w  = tid >> 6;
  const int l  = tid & 63;
  const int wr = (w >> 1) * 64;
  const int wc = (w & 1) * 64;
  const int lm = l & 15;
  const int lk = l >> 4;

  f32x4 acc[4][4];
#pragma unroll
  for (int m = 0; m < 4; ++m)
#pragma unroll
    for (int n = 0; n < 4; ++n)
      acc[m][n] = (f32x4){0.f, 0.f, 0.f, 0.f};

  const int mn = m0 < n0 ? m0 : n0;
  const int ktiles = (mn + 128) >> 5;   // nonzero k <= min(m0,n0)+127

  const int srow = l >> 2;          // 0..15
  const int scol = (l & 3) * 8;     // element offset (8 bf16 = 16B)

#define STAGE(kt, b)                                                                   \
  {                                                                                    \
    const int k0_ = (kt) * 32;                                                         \
    _Pragma("unroll")                                                                  \
    for (int c = 0; c < 2; ++c) {                                                      \
      const int r0 = (w * 2 + c) * 16;                                                 \
      GLOAD_LDS16(&As[b][r0 * 32], A + (size_t)(m0 + r0 + srow) * N + k0_ + scol);     \
      GLOAD_LDS16(&Bs[b][r0 * 32], A + (size_t)(n0 + r0 + srow) * N + k0_ + scol);     \
    }                                                                                  \
  }

  STAGE(0, 0);
  __syncthreads();   // vmcnt(0)+barrier: tile 0 staged

  for (int kt = 0; kt < ktiles; ++kt) {
    const int cur = kt & 1;
    if (kt + 1 < ktiles)
      STAGE(kt + 1, cur ^ 1);   // prefetch next tile; lands by the syncthreads below

    short8 af[4], bfr[4];
#pragma unroll
    for (int m = 0; m < 4; ++m)
      af[m] = *(const short8*)(&As[cur][(wr + m * 16 + lm) * 32 + lk * 8]);
#pragma unroll
    for (int n = 0; n < 4; ++n)
      bfr[n] = *(const short8*)(&Bs[cur][(wc + n * 16 + lm) * 32 + lk * 8]);

#pragma unroll
    for (int m = 0; m < 4; ++m)
#pragma unroll
      for (int n = 0; n < 4; ++n)
        acc[m][n] = __builtin_amdgcn_mfma_f32_16x16x32_bf16(af[m], bfr[n], acc[m][n], 0, 0, 0);

    __syncthreads();   // drains vmcnt (prefetch landed) + all waves done reading cur
  }
#undef STAGE

  // C/D layout: col = lane&15, row = (lane>>4)*4 + reg
#pragma unroll
  for (int m = 0; m < 4; ++m) {
    const int row = m0 + wr + m * 16 + lk * 4;
#pragma unroll
    for (int n = 0; n < 4; ++n) {
      const int col = n0 + wc + n * 16 + lm;
#pragma unroll
      for (int r = 0; r < 4; ++r)
        C[(size_t)(row + r) * N + col] = acc[m][n][r];
    }
  }
}

// ---------------------------------------------------------------------------
extern "C" void kernel_launch(void* const* d_in, const int* in_sizes, int n_in,
                              void* d_out, int out_size, void* d_ws, size_t ws_size,
                              hipStream_t stream) {
  const float* x  = (const float*)d_in[0];
  const float* W1 = (const float*)d_in[1];
  const float* b1 = (const float*)d_in[2];
  const float* W2 = (const float*)d_in[3];
  const float* b2 = (const float*)d_in[4];
  const float* W3 = (const float*)d_in[5];
  const float* b3 = (const float*)d_in[6];
  float* C = (float*)d_out;

  // ws: [0,8K) W2b bf16; [8K,9K) W1n; [12K,12.5K) b1n; [16K,16K+8M) A bf16
  __hip_bfloat16* W2b = (__hip_bfloat16*)d_ws;
  float* W1n = (float*)((char*)d_ws + 8192);
  float* b1n = (float*)((char*)d_ws + 12288);
  __hip_bfloat16* A = (__hip_bfloat16*)((char*)d_ws + 16384);

  prep_w<<<dim3(1), dim3(256), 0, stream>>>(W2, W1, b1, W2b, W1n, b1n);
  build_A_mfma<<<dim3(8704), dim3(256), 0, stream>>>(x, W1n, b1n, W2b, b2, W3, b3, A);
  gemm_ata<<<dim3(16, 16), dim3(256), 0, stream>>>(A, C);
  // ATTRIBUTION: second, idempotent gemm launch.  dur_us(this round) minus
  // dur_us(round 9) == one gemm_ata duration.  Same output C either way.
  gemm_ata<<<dim3(16, 16), dim3(256), 0, stream>>>(A, C);
}

// Round 14
// 183.743 us; speedup vs baseline: 1.1787x; 1.1787x over previous
//
#include <hip/hip_runtime.h>
#include <hip/hip_bf16.h>

#define N 2048

using f32x2  = __attribute__((ext_vector_type(2))) float;
using f32x4  = __attribute__((ext_vector_type(4))) float;
using short8 = __attribute__((ext_vector_type(8))) short;

// async global->LDS, 16B per lane; LDS dest = wave-uniform base + lane*16
#define GLOAD_LDS16(dst, src)                                                        \
  __builtin_amdgcn_global_load_lds((const __attribute__((address_space(1))) void*)(src), \
                                   (__attribute__((address_space(3))) void*)(dst), 16, 0, 0)

// ---------------------------------------------------------------------------
// Kernel 0: weights-only prep (1 block).  W2 -> bf16 [32][128]; W1,b1 pre-
// scaled by -log2(e) so the MLP inner loop feeds v_exp_f32 (2^t' = e^-t).
// ---------------------------------------------------------------------------
__global__ void prep_w(const float* __restrict__ W2, const float* __restrict__ W1,
                       const float* __restrict__ b1,
                       __hip_bfloat16* __restrict__ W2b,
                       float* __restrict__ W1n, float* __restrict__ b1n) {
  const int tid = threadIdx.x;   // 256 threads
  const float c = -1.4426950408889634f;  // -log2(e)
#pragma unroll
  for (int q = 0; q < 16; ++q)
    W2b[q * 256 + tid] = __float2bfloat16(W2[q * 256 + tid]);
  W1n[tid] = W1[tid] * c;
  if (tid < 128) b1n[tid] = b1[tid] * c;
}

// ---------------------------------------------------------------------------
// Kernel 1: build A = K^T (bf16) with MFMA layer-2.  BYTE-IDENTICAL to
// round-9 (passed, ~85-90 us).  Grid 8704: t < 8256 upper-tri MLP blocks;
// t >= 8256 band-zero blocks covering every lower-triangle element the
// gemm's k-clip can read.
// ---------------------------------------------------------------------------
__global__ __launch_bounds__(256) void build_A_mfma(
    const float* __restrict__ x,
    const float* __restrict__ W1n,             // [128][2], pre-scaled -log2e
    const float* __restrict__ b1n,             // [128],    pre-scaled -log2e
    const __hip_bfloat16* __restrict__ W2b,    // [32][128] bf16
    const float* __restrict__ b2,              // [32]
    const float* __restrict__ W3,              // [32]
    const float* __restrict__ b3,              // [1]
    __hip_bfloat16* __restrict__ A)            // [N][N], A[j][i]
{
  const int t = blockIdx.x;
  const int tid = threadIdx.x;

  if (t >= 8256) {               // band-zero block
    const int z = t - 8256;      // 0..447
    const int p = z / 28, q = z % 28;
    int r = 1;                    // decode strict lower-tri pair (r > c) from q
    while ((r * (r + 1)) / 2 <= q) ++r;       // r in 1..7
    const int c2 = q - (r * (r - 1)) / 2;     // c in 0..r-1
    const int jj = (p * 8 + c2) * 16 + (tid >> 4);   // row j (block bj = c2 < r)
    const int ii = (p * 8 + r) * 16 + (tid & 15);    // col i (block bi = r)
    A[(size_t)jj * N + ii] = __float2bfloat16(0.0f); // i > j here always
    return;
  }

  // decode linear upper-tri block id: t = bj*(bj+1)/2 + bi, bi <= bj
  int bj = (int)((sqrtf(8.0f * (float)t + 1.0f) - 1.0f) * 0.5f);
  while ((bj + 1) * (bj + 2) / 2 <= t) ++bj;
  while (bj * (bj + 1) / 2 > t) --bj;
  const int bi = t - bj * (bj + 1) / 2;

  const int i0 = bi * 16, j0 = bj * 16;

  __shared__ float w1s[256];   // [k][2] pre-scaled
  __shared__ float b1s[128];
  w1s[tid] = W1n[tid & 255];
  if (tid < 128) b1s[tid] = b1n[tid];
  __syncthreads();

  const int w  = tid >> 6;
  const int l  = tid & 63;
  const int lm = l & 15;       // A-frag row (i-slot) / C col (o)
  const int lk = l >> 4;       // k-block-of-8 / C row-group

  const float xi = x[i0 + lm];
  float xj[4];
#pragma unroll
  for (int m = 0; m < 4; ++m) xj[m] = x[j0 + w * 4 + m];

  // W2 fragments (B^T row-major): lane holds W2[o=g*16+lm][kb*32+lk*8 .. +7]
  short8 wf[2][4];
#pragma unroll
  for (int g = 0; g < 2; ++g)
#pragma unroll
    for (int kb = 0; kb < 4; ++kb)
      wf[g][kb] = *(const short8*)(W2b + (g * 16 + lm) * 128 + kb * 32 + lk * 8);

  const float b2v[2] = {b2[lm], b2[16 + lm]};
  f32x4 acc[4][2];
#pragma unroll
  for (int m = 0; m < 4; ++m)
#pragma unroll
    for (int g = 0; g < 2; ++g)
      acc[m][g] = (f32x4){b2v[g], b2v[g], b2v[g], b2v[g]};

#pragma unroll
  for (int kb = 0; kb < 4; ++kb) {
    // xi-dependent half of layer 1, shared across the 4 j's of this wave-slot
    f32x2 basep[4], w1bp[4];
#pragma unroll
    for (int e2 = 0; e2 < 4; ++e2) {
      const int k = kb * 32 + lk * 8 + e2 * 2;
      basep[e2] = (f32x2){fmaf(w1s[2 * k],     xi, b1s[k]),
                          fmaf(w1s[2 * k + 2], xi, b1s[k + 1])};
      w1bp[e2]  = (f32x2){w1s[2 * k + 1], w1s[2 * k + 3]};
    }
#pragma unroll
    for (int m = 0; m < 4; ++m) {
      const f32x2 xj2 = (f32x2){xj[m], xj[m]};
      __attribute__((ext_vector_type(4))) unsigned pk;
#pragma unroll
      for (int e2 = 0; e2 < 4; ++e2) {
        // h = sigmoid(t_orig) = 1/(1 + 2^t'),  t' = -log2e * t_orig
        const f32x2 t01 = __builtin_elementwise_fma(w1bp[e2], xj2, basep[e2]); // v_pk_fma_f32
        f32x2 e01;
        e01[0] = __builtin_amdgcn_exp2f(t01[0]);
        e01[1] = __builtin_amdgcn_exp2f(t01[1]);
        const f32x2 d01 = e01 + (f32x2){1.0f, 1.0f};                           // v_pk_add_f32
        const float h0 = __builtin_amdgcn_rcpf(d01[0]);   // t'->+inf: rcp(inf)=0 OK
        const float h1 = __builtin_amdgcn_rcpf(d01[1]);
        // round-half-up + perm -> [hi16(u1)|hi16(u0)]  (round-4-verified pack)
        const unsigned u0 = __builtin_bit_cast(unsigned, h0) + 0x8000u;
        const unsigned u1 = __builtin_bit_cast(unsigned, h1) + 0x8000u;
        pk[e2] = __builtin_amdgcn_perm(u1, u0, 0x07060302u);
      }
      const short8 af = __builtin_bit_cast(short8, pk);
      acc[m][0] = __builtin_amdgcn_mfma_f32_16x16x32_bf16(af, wf[0][kb], acc[m][0], 0, 0, 0);
      acc[m][1] = __builtin_amdgcn_mfma_f32_16x16x32_bf16(af, wf[1][kb], acc[m][1], 0, 0, 0);
    }
  }

  // Epilogue: v = b3 + sum_o relu(layer2[pair][o]) * W3[o]
  // C/D: row(pair) = lk*4 + r, col(o) = lm (+16 for g=1)
  const float w3a = W3[lm], w3b = W3[16 + lm];
  const float b3v = b3[0];
  const int   rsel = l & 3;

#pragma unroll
  for (int m = 0; m < 4; ++m) {
    const int j = j0 + w * 4 + m;
    float v[4];
#pragma unroll
    for (int r = 0; r < 4; ++r) {
      float s = fmaf(fmaxf(acc[m][0][r], 0.0f), w3a,
                     fmaxf(acc[m][1][r], 0.0f) * w3b);
      s += __shfl_xor(s, 1);
      s += __shfl_xor(s, 2);
      s += __shfl_xor(s, 4);
      s += __shfl_xor(s, 8);
      v[r] = s + b3v;
    }
    const float sv = rsel == 0 ? v[0] : rsel == 1 ? v[1] : rsel == 2 ? v[2] : v[3];
    const int i = i0 + lk * 4 + rsel;
    if (lm < 4)
      A[(size_t)j * N + i] = __float2bfloat16(i <= j ? sv : 0.0f);
  }
}

// ---------------------------------------------------------------------------
// Kernel 2: C += A * A^T  (split-K2).  Same verified 2-phase dbuf K-loop as
// round-9; grid (16,16,2) = 512 blocks = 2/CU (TLP hides barrier-drain
// latency); each z-half covers half the block's k-range (max 32 steps vs 64
// -> critical path halved).  Epilogue: HW f32 atomic add into zeroed C.
// ---------------------------------------------------------------------------
__global__ __launch_bounds__(256) void gemm_ata_sk(
    const __hip_bfloat16* __restrict__ A, float* __restrict__ C)
{
  __shared__ __align__(16) __hip_bfloat16 As[2][128 * 32];  // 2 x 8 KB
  __shared__ __align__(16) __hip_bfloat16 Bs[2][128 * 32];  // 2 x 8 KB

  const int m0 = blockIdx.y * 128;
  const int n0 = blockIdx.x * 128;
  const int tid = threadIdx.x;
  const int w  = tid >> 6;
  const int l  = tid & 63;
  const int wr = (w >> 1) * 64;
  const int wc = (w & 1) * 64;
  const int lm = l & 15;
  const int lk = l >> 4;

  f32x4 acc[4][4];
#pragma unroll
  for (int m = 0; m < 4; ++m)
#pragma unroll
    for (int n = 0; n < 4; ++n)
      acc[m][n] = (f32x4){0.f, 0.f, 0.f, 0.f};

  const int mn   = m0 < n0 ? m0 : n0;
  const int ktot = (mn + 128) >> 5;        // 4..64 nonzero k-tiles
  const int half = (ktot + 1) >> 1;        // >= 2
  const int kbeg = blockIdx.z ? half : 0;
  const int kend = blockIdx.z ? ktot : half;   // kend > kbeg always (ktot >= 4)

  const int srow = l >> 2;          // 0..15
  const int scol = (l & 3) * 8;     // element offset (8 bf16 = 16B)

#define STAGE(kt, b)                                                                   \
  {                                                                                    \
    const int k0_ = (kt) * 32;                                                         \
    _Pragma("unroll")                                                                  \
    for (int c = 0; c < 2; ++c) {                                                      \
      const int r0 = (w * 2 + c) * 16;                                                 \
      GLOAD_LDS16(&As[b][r0 * 32], A + (size_t)(m0 + r0 + srow) * N + k0_ + scol);     \
      GLOAD_LDS16(&Bs[b][r0 * 32], A + (size_t)(n0 + r0 + srow) * N + k0_ + scol);     \
    }                                                                                  \
  }

  STAGE(kbeg, 0);
  __syncthreads();   // vmcnt(0)+barrier: first tile staged

  for (int kt = kbeg; kt < kend; ++kt) {
    const int cur = (kt - kbeg) & 1;
    if (kt + 1 < kend)
      STAGE(kt + 1, cur ^ 1);   // prefetch next tile; lands by the syncthreads below

    short8 af[4], bfr[4];
#pragma unroll
    for (int m = 0; m < 4; ++m)
      af[m] = *(const short8*)(&As[cur][(wr + m * 16 + lm) * 32 + lk * 8]);
#pragma unroll
    for (int n = 0; n < 4; ++n)
      bfr[n] = *(const short8*)(&Bs[cur][(wc + n * 16 + lm) * 32 + lk * 8]);

#pragma unroll
    for (int m = 0; m < 4; ++m)
#pragma unroll
      for (int n = 0; n < 4; ++n)
        acc[m][n] = __builtin_amdgcn_mfma_f32_16x16x32_bf16(af[m], bfr[n], acc[m][n], 0, 0, 0);

    __syncthreads();   // drains vmcnt (prefetch landed) + all waves done reading cur
  }
#undef STAGE

  // C/D layout: col = lane&15, row = (lane>>4)*4 + reg.  HW f32 atomic add
  // (fire-and-forget, device scope) -- C zero-initialized by hipMemsetAsync.
#pragma unroll
  for (int m = 0; m < 4; ++m) {
    const int row = m0 + wr + m * 16 + lk * 4;
#pragma unroll
    for (int n = 0; n < 4; ++n) {
      const int col = n0 + wc + n * 16 + lm;
#pragma unroll
      for (int r = 0; r < 4; ++r)
        unsafeAtomicAdd(&C[(size_t)(row + r) * N + col], acc[m][n][r]);
    }
  }
}

// ---------------------------------------------------------------------------
extern "C" void kernel_launch(void* const* d_in, const int* in_sizes, int n_in,
                              void* d_out, int out_size, void* d_ws, size_t ws_size,
                              hipStream_t stream) {
  const float* x  = (const float*)d_in[0];
  const float* W1 = (const float*)d_in[1];
  const float* b1 = (const float*)d_in[2];
  const float* W2 = (const float*)d_in[3];
  const float* b2 = (const float*)d_in[4];
  const float* W3 = (const float*)d_in[5];
  const float* b3 = (const float*)d_in[6];
  float* C = (float*)d_out;

  // ws: [0,8K) W2b bf16; [8K,9K) W1n; [12K,12.5K) b1n; [16K,16K+8M) A bf16
  __hip_bfloat16* W2b = (__hip_bfloat16*)d_ws;
  float* W1n = (float*)((char*)d_ws + 8192);
  float* b1n = (float*)((char*)d_ws + 12288);
  __hip_bfloat16* A = (__hip_bfloat16*)((char*)d_ws + 16384);

  hipMemsetAsync(C, 0, (size_t)N * N * sizeof(float), stream);  // split-K accumulator
  prep_w<<<dim3(1), dim3(256), 0, stream>>>(W2, W1, b1, W2b, W1n, b1n);
  build_A_mfma<<<dim3(8704), dim3(256), 0, stream>>>(x, W1n, b1n, W2b, b2, W3, b3, A);
  gemm_ata_sk<<<dim3(16, 16, 2), dim3(256), 0, stream>>>(A, C);
}